// Round 1
// baseline (1928.100 us; speedup 1.0000x reference)
//
#include <hip/hip_runtime.h>
#include <math.h>

#define NDIM   128
#define NHEADS 4
#define DH     32
#define NB     8
#define NSEQ   16384
#define NCHUNK 32
#define CHUNK  (NSEQ / NCHUNK)   // 512
#define TILE   128
#define NTILES (CHUNK / TILE)    // 4

// ---------------------------------------------------------------------------
// Kernel 1: per (b, chunk): compute k,v rows on the fly, stage exp(k) and v in
// LDS (XOR-swizzled, stride 128), accumulate partial context and softmax denom.
// ctxp[b,h,chunk, d*32+e] = sum_n exp(k_d[n]) * v_e[n]   (chunk-local)
// Sp  [b,h,chunk, d]      = sum_n exp(k_d[n])
// ---------------------------------------------------------------------------
__global__ __launch_bounds__(512, 1)
void k1_ctx_partial(const float* __restrict__ x, const float* __restrict__ w_qkv,
                    float* __restrict__ ctxp, float* __restrict__ Sp) {
  __shared__ float ek_lds[TILE * 128];   // 64 KiB  exp(k) [col][row^swz]
  __shared__ float v_lds[TILE * 128];    // 64 KiB  v      [col][row^swz]
  const int b     = blockIdx.y;
  const int chunk = blockIdx.x;
  const int t     = threadIdx.x;
  const int c     = t & 127;   // column within tile
  const int part  = t >> 7;    // 0..3 -> 64 rows each of [k(128); v(128)]
  const int wave  = t >> 6;    // 0..7
  const int h     = wave >> 1;
  const int ehalf = wave & 1;
  const int lane  = t & 63;
  const int d     = lane & 31;
  const int ebase = ehalf * 16 + (lane >> 5) * 8;
  const int swc   = (c & 7) << 2;   // store-side XOR swizzle

  float ctx8[8];
#pragma unroll
  for (int j = 0; j < 8; ++j) ctx8[j] = 0.f;
  float s_acc = 0.f;

  const float* xbase = x + (size_t)b * NDIM * NSEQ;

  for (int tile = 0; tile < NTILES; ++tile) {
    const int n = chunk * CHUNK + tile * TILE + c;
    // ---- phase A: load x column into registers, compute 64 rows of [k;v]
    float xr[128];
    {
      const float* xp = xbase + n;
#pragma unroll
      for (int ch = 0; ch < 128; ++ch) xr[ch] = xp[(size_t)ch * NSEQ];
    }
    const int rbase = part * 64;                // rows rbase..rbase+63 of 256
    for (int i = 0; i < 64; i += 2) {
      const float4* w0 = (const float4*)(w_qkv + (size_t)(128 + rbase + i) * NDIM);
      const float4* w1 = (const float4*)(w_qkv + (size_t)(128 + rbase + i + 1) * NDIM);
      float a0 = 0.f, a1 = 0.f;
#pragma unroll
      for (int q4 = 0; q4 < 32; ++q4) {
        const float4 wv0 = w0[q4];
        const float4 wv1 = w1[q4];
        a0 += wv0.x * xr[q4*4+0]; a0 += wv0.y * xr[q4*4+1];
        a0 += wv0.z * xr[q4*4+2]; a0 += wv0.w * xr[q4*4+3];
        a1 += wv1.x * xr[q4*4+0]; a1 += wv1.y * xr[q4*4+1];
        a1 += wv1.z * xr[q4*4+2]; a1 += wv1.w * xr[q4*4+3];
      }
      if (part < 2) {  // k rows: store exp(k) (no max-sub needed; |logit| small)
        ek_lds[c * 128 + ((rbase + i)     ^ swc)] = __expf(a0);
        ek_lds[c * 128 + ((rbase + i + 1) ^ swc)] = __expf(a1);
      } else {         // v rows
        v_lds[c * 128 + ((rbase - 128 + i)     ^ swc)] = a0;
        v_lds[c * 128 + ((rbase - 128 + i + 1) ^ swc)] = a1;
      }
    }
    __syncthreads();
    // ---- phase B: accumulate partial context over this tile's 128 columns
    for (int cc = 0; cc < TILE; ++cc) {
      const int sw = (cc & 7) << 2;
      const float ek = ek_lds[cc * 128 + ((h * 32 + d) ^ sw)];
      const float4 v0 = *(const float4*)&v_lds[cc * 128 + ((h * 32 + ebase)     ^ sw)];
      const float4 v1 = *(const float4*)&v_lds[cc * 128 + ((h * 32 + ebase + 4) ^ sw)];
      ctx8[0] += ek * v0.x; ctx8[1] += ek * v0.y;
      ctx8[2] += ek * v0.z; ctx8[3] += ek * v0.w;
      ctx8[4] += ek * v1.x; ctx8[5] += ek * v1.y;
      ctx8[6] += ek * v1.z; ctx8[7] += ek * v1.w;
      s_acc += ek;
    }
    __syncthreads();
  }
  const size_t bh = (size_t)b * NHEADS + h;
  float* cp = ctxp + (bh * NCHUNK + chunk) * 1024 + d * 32 + ebase;
  *(float4*)cp       = make_float4(ctx8[0], ctx8[1], ctx8[2], ctx8[3]);
  *(float4*)(cp + 4) = make_float4(ctx8[4], ctx8[5], ctx8[6], ctx8[7]);
  if (ehalf == 0 && lane < 32) {
    Sp[(bh * NCHUNK + chunk) * 32 + d] = s_acc;
  }
}

// ---------------------------------------------------------------------------
// Kernel 2: reduce chunk partials -> ctx[b,h,d*32+e] = (sum ctxp) / (sum Sp_d)
// ---------------------------------------------------------------------------
__global__ void k2_reduce(const float* __restrict__ ctxp, const float* __restrict__ Sp,
                          float* __restrict__ ctx) {
  __shared__ float s_lds[32];
  const int bh  = blockIdx.x;   // 0..31
  const int tid = threadIdx.x;  // 256
  const int d   = tid >> 3;
  const int eg  = (tid & 7) * 4;
  float4 acc = make_float4(0.f, 0.f, 0.f, 0.f);
  float s = 0.f;
  for (int chk = 0; chk < NCHUNK; ++chk) {
    const float4 v4 = *(const float4*)&ctxp[((size_t)bh * NCHUNK + chk) * 1024 + d * 32 + eg];
    acc.x += v4.x; acc.y += v4.y; acc.z += v4.z; acc.w += v4.w;
    if (tid < 32) s += Sp[((size_t)bh * NCHUNK + chk) * 32 + tid];
  }
  if (tid < 32) s_lds[tid] = s;
  __syncthreads();
  const float inv = 1.0f / s_lds[d];
  float* cp = ctx + (size_t)bh * 1024 + d * 32 + eg;
  *(float4*)cp = make_float4(acc.x * inv, acc.y * inv, acc.z * inv, acc.w * inv);
}

// ---------------------------------------------------------------------------
// Kernel 3: per column n: q softmax*scale -> y = ctx^T q -> w_out @ y + b ->
// RMSNorm over channels -> store. Thread (c,p): column c, head/row-group p.
// ---------------------------------------------------------------------------
__global__ __launch_bounds__(512, 1)
void k3_out(const float* __restrict__ x, const float* __restrict__ w_qkv,
            const float* __restrict__ ctx, const float* __restrict__ w_out,
            const float* __restrict__ b_out, const float* __restrict__ g,
            float* __restrict__ out) {
  __shared__ float y_lds[TILE * 128];   // 64 KiB, XOR-swizzled like k1
  __shared__ float nrm_lds[4 * TILE];
  const int b = blockIdx.y;
  const int t = threadIdx.x;
  const int c = t & 127;
  const int p = t >> 7;
  const int n = blockIdx.x * TILE + c;
  const int swc = (c & 7) << 2;

  // ---- q logits for head p (rows p*32..p*32+31)
  float xr[128];
  {
    const float* xp = x + (size_t)b * NDIM * NSEQ + n;
#pragma unroll
    for (int ch = 0; ch < 128; ++ch) xr[ch] = xp[(size_t)ch * NSEQ];
  }
  float acc[32];
#pragma unroll
  for (int i = 0; i < 32; i += 2) {
    const float4* w0 = (const float4*)(w_qkv + (size_t)(p * 32 + i) * NDIM);
    const float4* w1 = (const float4*)(w_qkv + (size_t)(p * 32 + i + 1) * NDIM);
    float a0 = 0.f, a1 = 0.f;
#pragma unroll
    for (int q4 = 0; q4 < 32; ++q4) {
      const float4 wv0 = w0[q4];
      const float4 wv1 = w1[q4];
      a0 += wv0.x * xr[q4*4+0]; a0 += wv0.y * xr[q4*4+1];
      a0 += wv0.z * xr[q4*4+2]; a0 += wv0.w * xr[q4*4+3];
      a1 += wv1.x * xr[q4*4+0]; a1 += wv1.y * xr[q4*4+1];
      a1 += wv1.z * xr[q4*4+2]; a1 += wv1.w * xr[q4*4+3];
    }
    acc[i] = a0; acc[i + 1] = a1;
  }
  // ---- softmax over d (in-thread) * scale
  float m = acc[0];
#pragma unroll
  for (int i = 1; i < 32; ++i) m = fmaxf(m, acc[i]);
  float s = 0.f;
#pragma unroll
  for (int i = 0; i < 32; ++i) { acc[i] = __expf(acc[i] - m); s += acc[i]; }
  const float qsc = 0.17677669529663687f / s;   // scale = 32^-0.5
  // ---- y_p[e] = sum_d ctx[p][d][e] * qs[d]
  float y[32];
#pragma unroll
  for (int j = 0; j < 32; ++j) y[j] = 0.f;
  const float* cbase = ctx + ((size_t)b * NHEADS + p) * 1024;
#pragma unroll
  for (int dd = 0; dd < 32; ++dd) {
    const float qd = acc[dd] * qsc;
    const float4* cr = (const float4*)(cbase + dd * 32);
#pragma unroll
    for (int e4 = 0; e4 < 8; ++e4) {
      const float4 cv = cr[e4];
      y[e4*4+0] += cv.x * qd; y[e4*4+1] += cv.y * qd;
      y[e4*4+2] += cv.z * qd; y[e4*4+3] += cv.w * qd;
    }
  }
  // ---- exchange y across the 4 head-threads of this column
#pragma unroll
  for (int e4 = 0; e4 < 8; ++e4) {
    *(float4*)&y_lds[c * 128 + ((p * 32 + e4 * 4) ^ swc)] =
        make_float4(y[e4*4+0], y[e4*4+1], y[e4*4+2], y[e4*4+3]);
  }
  __syncthreads();
  float yr[128];
#pragma unroll
  for (int q4 = 0; q4 < 32; ++q4) {
    const float4 t4 = *(const float4*)&y_lds[c * 128 + ((q4 * 4) ^ swc)];
    yr[q4*4+0] = t4.x; yr[q4*4+1] = t4.y; yr[q4*4+2] = t4.z; yr[q4*4+3] = t4.w;
  }
  // ---- out rows o = p*32..p*32+31 : w_out @ y + b_out
  float outv[32];
  float pn = 0.f;
#pragma unroll
  for (int i = 0; i < 32; i += 2) {
    const int o0 = p * 32 + i;
    const float4* w0 = (const float4*)(w_out + (size_t)o0 * NDIM);
    const float4* w1 = (const float4*)(w_out + (size_t)(o0 + 1) * NDIM);
    float a0 = 0.f, a1 = 0.f;
#pragma unroll
    for (int q4 = 0; q4 < 32; ++q4) {
      const float4 wv0 = w0[q4];
      const float4 wv1 = w1[q4];
      a0 += wv0.x * yr[q4*4+0]; a0 += wv0.y * yr[q4*4+1];
      a0 += wv0.z * yr[q4*4+2]; a0 += wv0.w * yr[q4*4+3];
      a1 += wv1.x * yr[q4*4+0]; a1 += wv1.y * yr[q4*4+1];
      a1 += wv1.z * yr[q4*4+2]; a1 += wv1.w * yr[q4*4+3];
    }
    a0 += b_out[o0]; a1 += b_out[o0 + 1];
    outv[i] = a0; outv[i + 1] = a1;
    pn += a0 * a0 + a1 * a1;
  }
  // ---- RMSNorm over all 128 channels (4 partials per column)
  nrm_lds[p * TILE + c] = pn;
  __syncthreads();
  const float tot = nrm_lds[c] + nrm_lds[TILE + c] + nrm_lds[2 * TILE + c] + nrm_lds[3 * TILE + c];
  const float inv = 11.313708498984761f / fmaxf(sqrtf(tot), 1e-12f);  // sqrt(128)/max(nrm,eps)
  float* obase = out + ((size_t)b * NDIM + p * 32) * NSEQ + n;
#pragma unroll
  for (int i = 0; i < 32; ++i) {
    obase[(size_t)i * NSEQ] = outv[i] * inv * g[p * 32 + i];
  }
}

extern "C" void kernel_launch(void* const* d_in, const int* in_sizes, int n_in,
                              void* d_out, int out_size, void* d_ws, size_t ws_size,
                              hipStream_t stream) {
  const float* x     = (const float*)d_in[0];
  const float* w_qkv = (const float*)d_in[1];
  const float* w_out = (const float*)d_in[2];
  const float* b_out = (const float*)d_in[3];
  const float* g     = (const float*)d_in[4];
  float* out = (float*)d_out;

  float* wsf  = (float*)d_ws;
  float* ctxp = wsf;                                              // 8*4*32*1024 floats = 4 MiB
  float* Sp   = ctxp + (size_t)NB * NHEADS * NCHUNK * 1024;       // 8*4*32*32
  float* ctx  = Sp   + (size_t)NB * NHEADS * NCHUNK * 32;         // 8*4*1024

  hipLaunchKernelGGL(k1_ctx_partial, dim3(NCHUNK, NB), dim3(512), 0, stream,
                     x, w_qkv, ctxp, Sp);
  hipLaunchKernelGGL(k2_reduce, dim3(NB * NHEADS), dim3(256), 0, stream,
                     ctxp, Sp, ctx);
  hipLaunchKernelGGL(k3_out, dim3(NSEQ / TILE, NB), dim3(512), 0, stream,
                     x, w_qkv, ctx, w_out, b_out, g, out);
}

// Round 2
// 288.866 us; speedup vs baseline: 6.6747x; 6.6747x over previous
//
#include <hip/hip_runtime.h>
#include <math.h>

typedef unsigned short ushort_t;
typedef unsigned int uint_t;
typedef __attribute__((ext_vector_type(8))) short short8;
typedef __attribute__((ext_vector_type(4))) float f32x4;
typedef __attribute__((ext_vector_type(4))) uint_t uint4v;
typedef __attribute__((ext_vector_type(2))) uint_t uint2v;

#define NSEQ 16384
#define SCALE_Q 0.17677669529663687f   // 32^-0.5
#define RMS_K 11.313708498984761f      // sqrt(128)

__device__ __forceinline__ ushort_t f2bf(float f) {
  uint_t u = __builtin_bit_cast(uint_t, f);
  u += 0x7FFFu + ((u >> 16) & 1u);
  return (ushort_t)(u >> 16);
}
__device__ __forceinline__ uint_t f2bf2(float lo, float hi) {
  return (uint_t)f2bf(lo) | ((uint_t)f2bf(hi) << 16);
}
__device__ __forceinline__ float bf2f(ushort_t u) {
  return __builtin_bit_cast(float, ((uint_t)u) << 16);
}
// swizzled ushort-index into a [row][128] bf16 LDS array (256B rows)
// slot-XOR (bank spread for 16-lane row-varied reads) + word-XOR on row bit4
__device__ __forceinline__ int swz(int row, int col) {
  int slot = (col >> 3) ^ (row & 7);
  int w2 = ((col >> 1) & 3) ^ (((row >> 4) & 1) << 1);
  return row * 128 + slot * 8 + w2 * 2 + (col & 1);
}
// 16B frag read; pp = (row>>4)&1 un-permutes the word swizzle (compile-time)
__device__ __forceinline__ short8 ldfrag(const ushort_t* lds, int row, int col8, int pp) {
  int slot = (col8 >> 3) ^ (row & 7);
  const uint4v q = *(const uint4v*)&lds[row * 128 + slot * 8];
  uint4v r;
  if (pp) { r.x = q.z; r.y = q.w; r.z = q.x; r.w = q.y; } else { r = q; }
  return __builtin_bit_cast(short8, r);
}
#define MFMA(a, b, c) __builtin_amdgcn_mfma_f32_16x16x32_bf16((a), (b), (c), 0, 0, 0)

// ---------------------------------------------------------------------------
// kP: pack weights to bf16 in MFMA B-fragment order.
// frag layout: [kstep][Ntile][lane 64][8], elem j -> k = kstep*32+(lane>>4)*8+j,
// col = Ntile*16 + (lane&15)
// ---------------------------------------------------------------------------
__global__ void kP(const float* __restrict__ w_qkv, const float* __restrict__ w_out,
                   ushort_t* __restrict__ wkv_pk, ushort_t* __restrict__ wq_pk,
                   ushort_t* __restrict__ wout_pk) {
  const int i = blockIdx.x * 256 + threadIdx.x;
  const int j = i & 7, lane = (i >> 3) & 63;
  const int l15 = lane & 15, l4 = lane >> 4;
  if (i < 32768) {                       // w_kv^T: cols = kv rows 0..255 (global rows 128..383)
    const int rest = i >> 9, Nt = rest & 15, kk = rest >> 4;
    wkv_pk[i] = f2bf(w_qkv[(128 + Nt * 16 + l15) * 128 + kk * 32 + l4 * 8 + j]);
  } else if (i < 49152) {                // w_q^T: cols = q rows 0..127
    const int i2 = i - 32768, rest = i2 >> 9, Nt = rest & 7, kk = rest >> 3;
    wq_pk[i2] = f2bf(w_qkv[(Nt * 16 + l15) * 128 + kk * 32 + l4 * 8 + j]);
  } else if (i < 65536) {                // w_out^T: cols = outc, k = hid
    const int i2 = i - 49152, rest = i2 >> 9, Nt = rest & 7, kk = rest >> 3;
    wout_pk[i2] = f2bf(w_out[(Nt * 16 + l15) * 128 + kk * 32 + l4 * 8 + j]);
  }
}

// ---------------------------------------------------------------------------
// kA: per (b, 512-n chunk): kv^T = x^T w_kv^T (MFMA), exp(k) & v -> swizzled
// LDS, ctx_partial += exp(K) V^T (MFMA over n), S_d partial. Atomic-reduced
// into ctx_acc / S_glob.
// ---------------------------------------------------------------------------
__global__ __launch_bounds__(512, 2)
void kA(const float* __restrict__ x, const ushort_t* __restrict__ wkv_pk,
        float* __restrict__ ctx_acc, float* __restrict__ S_glob) {
  __shared__ ushort_t xs[2][16384];   // [n 128][c 128] bf16, double-buffered
  __shared__ ushort_t eks[16384];     // [d 128][n 128] exp(k) bf16
  __shared__ ushort_t vs[16384];      // [e 128][n 128] v bf16
  __shared__ float S_lds[128];
  const int b = blockIdx.y, blk = blockIdx.x;
  const int tid = threadIdx.x, wave = tid >> 6, lane = tid & 63;
  const int mg = wave >> 2, ng = wave & 3;   // proj: n-group, kvrow-group
  const int h = wave >> 1, dt = wave & 1;    // ctx: head, d-tile
  const int l15 = lane & 15, l4 = lane >> 4;
  if (tid < 128) S_lds[tid] = 0.f;

  // persistent B-frags (w_kv^T): 16 frags = 64 VGPR
  short8 wf[4][4];
#pragma unroll
  for (int kk = 0; kk < 4; ++kk)
#pragma unroll
    for (int nt = 0; nt < 4; ++nt)
      wf[kk][nt] = *(const short8*)&wkv_pk[((kk * 16 + ng * 4 + nt) * 64 + lane) * 8];

  const f32x4 fzero = {0.f, 0.f, 0.f, 0.f};
  f32x4 cacc[2]; cacc[0] = fzero; cacc[1] = fzero;
  float sacc[4] = {0.f, 0.f, 0.f, 0.f};

  const int sn = tid & 127, cb = (tid >> 7) * 32;
  const float* xb = x + (size_t)b * 128 * NSEQ + blk * 512 + sn;
  float pf[32];
#pragma unroll
  for (int i = 0; i < 32; ++i) pf[i] = xb[(size_t)(cb + i) * NSEQ];

  for (int s = 0; s < 4; ++s) {
    const int p = s & 1;
    __syncthreads();
    {  // write prefetched x -> xs[p] (bf16 pairs, swizzled)
      uint_t* xw = (uint_t*)xs[p];
#pragma unroll
      for (int i = 0; i < 32; i += 2)
        xw[swz(sn, cb + i) >> 1] = f2bf2(pf[i], pf[i + 1]);
    }
    if (s < 3) {  // issue next subtile's loads; overlap with compute below
#pragma unroll
      for (int i = 0; i < 32; ++i) pf[i] = xb[(size_t)(cb + i) * NSEQ + (s + 1) * 128];
    }
    __syncthreads();
    // ---- projection: pacc[mt][nt] = kv^T tile (rows n, cols kvrow)
    f32x4 pacc[4][4];
#pragma unroll
    for (int mt = 0; mt < 4; ++mt)
#pragma unroll
      for (int nt = 0; nt < 4; ++nt) pacc[mt][nt] = fzero;
#pragma unroll
    for (int kk = 0; kk < 4; ++kk) {
      short8 af[4];
#pragma unroll
      for (int mt = 0; mt < 4; ++mt)
        af[mt] = ldfrag(xs[p], mg * 64 + mt * 16 + l15, kk * 32 + l4 * 8, mt & 1);
#pragma unroll
      for (int mt = 0; mt < 4; ++mt)
#pragma unroll
        for (int nt = 0; nt < 4; ++nt)
          pacc[mt][nt] = MFMA(af[mt], wf[kk][nt], pacc[mt][nt]);
    }
    // ---- epilogue: exp(k)->eks, v->vs (bf16 pairs along n)
#pragma unroll
    for (int nt = 0; nt < 4; ++nt) {
      const int kvr = ng * 64 + nt * 16 + l15;
#pragma unroll
      for (int mt = 0; mt < 4; ++mt) {
        const int nq = mg * 64 + mt * 16 + l4 * 4;
        f32x4 v = pacc[mt][nt];
        if (ng < 2) {
          float e0 = __expf(v.x), e1 = __expf(v.y), e2 = __expf(v.z), e3 = __expf(v.w);
          sacc[nt] += (e0 + e1) + (e2 + e3);
          uint_t* ew = (uint_t*)eks;
          ew[swz(kvr, nq) >> 1] = f2bf2(e0, e1);
          ew[swz(kvr, nq + 2) >> 1] = f2bf2(e2, e3);
        } else {
          uint_t* vw = (uint_t*)vs;
          vw[swz(kvr - 128, nq) >> 1] = f2bf2(v.x, v.y);
          vw[swz(kvr - 128, nq + 2) >> 1] = f2bf2(v.z, v.w);
        }
      }
    }
    __syncthreads();
    // ---- ctx MFMA: cacc[et] += exp(K)[d-tile] * V^T[e-tile], K = 128 n
    const int drow = h * 32 + dt * 16 + l15;
#pragma unroll
    for (int kk2 = 0; kk2 < 4; ++kk2) {
      short8 ea = ldfrag(eks, drow, kk2 * 32 + l4 * 8, dt);
#pragma unroll
      for (int et = 0; et < 2; ++et) {
        short8 vb = ldfrag(vs, h * 32 + et * 16 + l15, kk2 * 32 + l4 * 8, et);
        cacc[et] = MFMA(ea, vb, cacc[et]);
      }
    }
  }
  // ---- reduce: global atomics
#pragma unroll
  for (int et = 0; et < 2; ++et) {
    float* dst = &ctx_acc[((((b * 4 + h) * 2 + dt) * 2 + et) * 64 + lane) * 4];
    atomicAdd(dst + 0, cacc[et].x);
    atomicAdd(dst + 1, cacc[et].y);
    atomicAdd(dst + 2, cacc[et].z);
    atomicAdd(dst + 3, cacc[et].w);
  }
  if (ng < 2) {
#pragma unroll
    for (int nt = 0; nt < 4; ++nt)
      atomicAdd(&S_lds[ng * 64 + nt * 16 + l15], sacc[nt]);
  }
  __syncthreads();
  if (tid < 128) atomicAdd(&S_glob[b * 128 + tid], S_lds[tid]);
}

// ---------------------------------------------------------------------------
// kB: ctx = ctx_acc / S, packed to bf16 B-fragment order for kC.
// ---------------------------------------------------------------------------
__global__ void kB(const float* __restrict__ ctx_acc, const float* __restrict__ S_glob,
                   ushort_t* __restrict__ ctx_pk) {
  const int bh = blockIdx.x;             // b*4 + h
  const int b = bh >> 2, hh = bh & 3;
  const int t = threadIdx.x;             // 256
  const int lane = t & 63, dtet = t >> 6, dt = dtet >> 1, et = dtet & 1;
  const int l15 = lane & 15, q = lane >> 4;
  const f32x4 c4 = *(const f32x4*)&ctx_acc[(((bh * 2 + dt) * 2 + et) * 64 + lane) * 4];
  const int dbase = dt * 16 + q * 4;
  ushort_t o[4];
#pragma unroll
  for (int r = 0; r < 4; ++r) {
    const float S = S_glob[b * 128 + hh * 32 + dbase + r];
    o[r] = f2bf(c4[r] / S);
  }
  const int lp = l15 + (((dbase >> 3) & 3) << 4);
  uint2v w;
  w.x = (uint_t)o[0] | ((uint_t)o[1] << 16);
  w.y = (uint_t)o[2] | ((uint_t)o[3] << 16);
  *(uint2v*)&ctx_pk[((bh * 2 + et) * 64 + lp) * 8 + (q & 1) * 4] = w;
}

// ---------------------------------------------------------------------------
// kC: q^T = x^T w_q^T -> softmax(d)*scale -> out_att^T = qhat^T ctx ->
// out^T = y^T w_out^T + b -> RMSNorm(channels) -> store.
// ---------------------------------------------------------------------------
__global__ __launch_bounds__(512, 2)
void kC(const float* __restrict__ x, const ushort_t* __restrict__ wq_pk,
        const ushort_t* __restrict__ wout_pk, const ushort_t* __restrict__ ctx_pk,
        const float* __restrict__ b_out, const float* __restrict__ g,
        float* __restrict__ out) {
  __shared__ ushort_t xs[2][16384];   // x bf16 [n][c]; current parity reused for qhat [n][qrow]
  __shared__ ushort_t qlog[16384];    // q logits bf16 [qrow][n]
  __shared__ ushort_t yT[16384];      // y bf16 [n][hid]
  __shared__ float nrm[128];
  __shared__ float bias_l[128], g_l[128];
  const int b = blockIdx.y, blk = blockIdx.x;
  const int tid = threadIdx.x, wave = tid >> 6, lane = tid & 63;
  const int mg = wave >> 1, ng = wave & 1;
  const int l15 = lane & 15, l4 = lane >> 4;
  if (tid < 128) { bias_l[tid] = b_out[tid]; g_l[tid] = g[tid]; }

  // persistent ctx B-frags: wave's Nt = ng*4+nt -> (h, et) = (Nt>>1, Nt&1)
  short8 cfr[4];
#pragma unroll
  for (int nt = 0; nt < 4; ++nt) {
    const int Nt = ng * 4 + nt, hh = Nt >> 1, et = Nt & 1;
    cfr[nt] = *(const short8*)&ctx_pk[(((b * 4 + hh) * 2 + et) * 64 + lane) * 8];
  }
  const f32x4 fzero = {0.f, 0.f, 0.f, 0.f};
  const int sn = tid & 127, cb = (tid >> 7) * 32;
  const float* xb = x + (size_t)b * 128 * NSEQ + blk * 512 + sn;
  float pf[32];
#pragma unroll
  for (int i = 0; i < 32; ++i) pf[i] = xb[(size_t)(cb + i) * NSEQ];

  for (int s = 0; s < 4; ++s) {
    const int p = s & 1;
    __syncthreads();
    if (tid < 128) nrm[tid] = 0.f;
    {
      uint_t* xw = (uint_t*)xs[p];
#pragma unroll
      for (int i = 0; i < 32; i += 2)
        xw[swz(sn, cb + i) >> 1] = f2bf2(pf[i], pf[i + 1]);
    }
    if (s < 3) {
#pragma unroll
      for (int i = 0; i < 32; ++i) pf[i] = xb[(size_t)(cb + i) * NSEQ + (s + 1) * 128];
    }
    __syncthreads();
    // ---- Q projection (transposed): pacc[mt][nt], rows n, cols qrow
    f32x4 pacc[2][4];
#pragma unroll
    for (int mt = 0; mt < 2; ++mt)
#pragma unroll
      for (int nt = 0; nt < 4; ++nt) pacc[mt][nt] = fzero;
#pragma unroll
    for (int kk = 0; kk < 4; ++kk) {
      short8 wqf[4];
#pragma unroll
      for (int nt = 0; nt < 4; ++nt)
        wqf[nt] = *(const short8*)&wq_pk[((kk * 8 + ng * 4 + nt) * 64 + lane) * 8];
      short8 af[2];
#pragma unroll
      for (int mt = 0; mt < 2; ++mt)
        af[mt] = ldfrag(xs[p], mg * 32 + mt * 16 + l15, kk * 32 + l4 * 8, mt & 1);
#pragma unroll
      for (int mt = 0; mt < 2; ++mt)
#pragma unroll
        for (int nt = 0; nt < 4; ++nt)
          pacc[mt][nt] = MFMA(af[mt], wqf[nt], pacc[mt][nt]);
    }
    {
      uint_t* qw = (uint_t*)qlog;
#pragma unroll
      for (int nt = 0; nt < 4; ++nt) {
        const int qrow = ng * 64 + nt * 16 + l15;
#pragma unroll
        for (int mt = 0; mt < 2; ++mt) {
          const int nq = mg * 32 + mt * 16 + l4 * 4;
          qw[swz(qrow, nq) >> 1] = f2bf2(pacc[mt][nt].x, pacc[mt][nt].y);
          qw[swz(qrow, nq + 2) >> 1] = f2bf2(pacc[mt][nt].z, pacc[mt][nt].w);
        }
      }
    }
    __syncthreads();
    // ---- softmax over d (in-thread), write qhat^T [n][qrow] into xs[p]
    {
      const int n2 = tid & 127, hq = tid >> 7;
      float lv[32];
#pragma unroll
      for (int i = 0; i < 32; ++i) lv[i] = bf2f(qlog[swz(hq * 32 + i, n2)]);
      float m = lv[0];
#pragma unroll
      for (int i = 1; i < 32; ++i) m = fmaxf(m, lv[i]);
      float ssum = 0.f;
#pragma unroll
      for (int i = 0; i < 32; ++i) { lv[i] = __expf(lv[i] - m); ssum += lv[i]; }
      const float qs = SCALE_Q / ssum;
      uint_t* hw = (uint_t*)xs[p];
#pragma unroll
      for (int i = 0; i < 32; i += 2)
        hw[swz(n2, hq * 32 + i) >> 1] = f2bf2(lv[i] * qs, lv[i + 1] * qs);
    }
    __syncthreads();
    // ---- out_att: oacc[mt][nt] = qhat^T * ctx (K = 32, one step)
    f32x4 oacc[2][4];
#pragma unroll
    for (int mt = 0; mt < 2; ++mt)
#pragma unroll
      for (int nt = 0; nt < 4; ++nt) oacc[mt][nt] = fzero;
#pragma unroll
    for (int hi = 0; hi < 2; ++hi) {
      const int h2 = ng * 2 + hi;
      short8 af[2];
#pragma unroll
      for (int mt = 0; mt < 2; ++mt)
        af[mt] = ldfrag(xs[p], mg * 32 + mt * 16 + l15, h2 * 32 + l4 * 8, mt & 1);
#pragma unroll
      for (int et = 0; et < 2; ++et) {
        const int nt = hi * 2 + et;
#pragma unroll
        for (int mt = 0; mt < 2; ++mt)
          oacc[mt][nt] = MFMA(af[mt], cfr[nt], oacc[mt][nt]);
      }
    }
    // ---- write yT [n][hid]: lane-pair shuffle to pack bf16 pairs along hid
    {
      uint_t* yw = (uint_t*)yT;
#pragma unroll
      for (int nt = 0; nt < 4; ++nt) {
        const int hid = ng * 64 + nt * 16 + l15;
        const int hb = hid & ~1;
#pragma unroll
        for (int mt = 0; mt < 2; ++mt) {
          const int nq = mg * 32 + mt * 16 + l4 * 4;
          f32x4 v = oacc[mt][nt];
          float o0 = __shfl_xor(v.x, 1), o1 = __shfl_xor(v.y, 1);
          float o2 = __shfl_xor(v.z, 1), o3 = __shfl_xor(v.w, 1);
          if ((lane & 1) == 0) {
            yw[swz(nq, hb) >> 1] = f2bf2(v.x, o0);
            yw[swz(nq + 1, hb) >> 1] = f2bf2(v.y, o1);
          } else {
            yw[swz(nq + 2, hb) >> 1] = f2bf2(o2, v.z);
            yw[swz(nq + 3, hb) >> 1] = f2bf2(o3, v.w);
          }
        }
      }
    }
    __syncthreads();
    // ---- final GEMM: facc = y^T w_out^T
    f32x4 facc[2][4];
#pragma unroll
    for (int mt = 0; mt < 2; ++mt)
#pragma unroll
      for (int nt = 0; nt < 4; ++nt) facc[mt][nt] = fzero;
#pragma unroll
    for (int kk = 0; kk < 4; ++kk) {
      short8 wof[4];
#pragma unroll
      for (int nt = 0; nt < 4; ++nt)
        wof[nt] = *(const short8*)&wout_pk[((kk * 8 + ng * 4 + nt) * 64 + lane) * 8];
      short8 af[2];
#pragma unroll
      for (int mt = 0; mt < 2; ++mt)
        af[mt] = ldfrag(yT, mg * 32 + mt * 16 + l15, kk * 32 + l4 * 8, mt & 1);
#pragma unroll
      for (int mt = 0; mt < 2; ++mt)
#pragma unroll
        for (int nt = 0; nt < 4; ++nt)
          facc[mt][nt] = MFMA(af[mt], wof[nt], facc[mt][nt]);
    }
    // ---- bias + sum of squares (RMSNorm over 128 channels)
    float sq[2][4] = {{0.f, 0.f, 0.f, 0.f}, {0.f, 0.f, 0.f, 0.f}};
#pragma unroll
    for (int nt = 0; nt < 4; ++nt) {
      const int outc = ng * 64 + nt * 16 + l15;
      const float bb = bias_l[outc];
#pragma unroll
      for (int mt = 0; mt < 2; ++mt) {
        facc[mt][nt].x += bb; facc[mt][nt].y += bb;
        facc[mt][nt].z += bb; facc[mt][nt].w += bb;
        sq[mt][0] += facc[mt][nt].x * facc[mt][nt].x;
        sq[mt][1] += facc[mt][nt].y * facc[mt][nt].y;
        sq[mt][2] += facc[mt][nt].z * facc[mt][nt].z;
        sq[mt][3] += facc[mt][nt].w * facc[mt][nt].w;
      }
    }
#pragma unroll
    for (int mt = 0; mt < 2; ++mt)
#pragma unroll
      for (int r = 0; r < 4; ++r) {
        sq[mt][r] += __shfl_xor(sq[mt][r], 1);
        sq[mt][r] += __shfl_xor(sq[mt][r], 2);
        sq[mt][r] += __shfl_xor(sq[mt][r], 4);
        sq[mt][r] += __shfl_xor(sq[mt][r], 8);
      }
    if (l15 == 0) {
#pragma unroll
      for (int mt = 0; mt < 2; ++mt)
#pragma unroll
        for (int r = 0; r < 4; ++r)
          atomicAdd(&nrm[mg * 32 + mt * 16 + l4 * 4 + r], sq[mt][r]);
    }
    __syncthreads();
    // ---- normalize + store (float4 along n)
#pragma unroll
    for (int mt = 0; mt < 2; ++mt) {
      const int nq = mg * 32 + mt * 16 + l4 * 4;
      const float inv0 = RMS_K / fmaxf(sqrtf(nrm[nq + 0]), 1e-12f);
      const float inv1 = RMS_K / fmaxf(sqrtf(nrm[nq + 1]), 1e-12f);
      const float inv2 = RMS_K / fmaxf(sqrtf(nrm[nq + 2]), 1e-12f);
      const float inv3 = RMS_K / fmaxf(sqrtf(nrm[nq + 3]), 1e-12f);
#pragma unroll
      for (int nt = 0; nt < 4; ++nt) {
        const int outc = ng * 64 + nt * 16 + l15;
        const float gg = g_l[outc];
        f32x4 o;
        o.x = facc[mt][nt].x * inv0 * gg;
        o.y = facc[mt][nt].y * inv1 * gg;
        o.z = facc[mt][nt].z * inv2 * gg;
        o.w = facc[mt][nt].w * inv3 * gg;
        *(f32x4*)&out[(size_t)(b * 128 + outc) * NSEQ + blk * 512 + s * 128 + nq] = o;
      }
    }
  }
}

extern "C" void kernel_launch(void* const* d_in, const int* in_sizes, int n_in,
                              void* d_out, int out_size, void* d_ws, size_t ws_size,
                              hipStream_t stream) {
  const float* x = (const float*)d_in[0];
  const float* w_qkv = (const float*)d_in[1];
  const float* w_out = (const float*)d_in[2];
  const float* b_out = (const float*)d_in[3];
  const float* g = (const float*)d_in[4];
  float* out = (float*)d_out;

  float* ctx_acc = (float*)d_ws;                     // 32768 f32
  float* S_glob = ctx_acc + 32768;                   // 1024 f32
  ushort_t* wkv_pk = (ushort_t*)(S_glob + 1024);     // 32768 ush
  ushort_t* wq_pk = wkv_pk + 32768;                  // 16384 ush
  ushort_t* wout_pk = wq_pk + 16384;                 // 16384 ush
  ushort_t* ctx_pk = wout_pk + 16384;                // 32768 ush

  hipMemsetAsync(d_ws, 0, (32768 + 1024) * sizeof(float), stream);
  hipLaunchKernelGGL(kP, dim3(256), dim3(256), 0, stream, w_qkv, w_out, wkv_pk, wq_pk, wout_pk);
  hipLaunchKernelGGL(kA, dim3(32, 8), dim3(512), 0, stream, x, wkv_pk, ctx_acc, S_glob);
  hipLaunchKernelGGL(kB, dim3(32), dim3(256), 0, stream, ctx_acc, S_glob, ctx_pk);
  hipLaunchKernelGGL(kC, dim3(32, 8), dim3(512), 0, stream, x, wq_pk, wout_pk, ctx_pk, b_out, g, out);
}